// Round 3
// baseline (887.974 us; speedup 1.0000x reference)
//
#include <hip/hip_runtime.h>
#include <math.h>

#define BATCH 4
#define SEQL 1024
#define DMODEL 256
#define DINNER 512
#define DSTATE 16
#define DTRANK 16
#define NLAYERS 4
#define MTOT (BATCH * SEQL)  // 4096

// LDS swizzle for per-(chunk,pos) time-series arrays: slot(t) = (t&63)*17 + (t>>6)
#define IDX(t) ((((t) & 63) * 17) + ((t) >> 6))

static __device__ __forceinline__ float siluf(float x) {
    return x / (1.0f + expf(-x));
}
static __device__ __forceinline__ float softplusf(float x) {
    return (x > 0.0f) ? (x + log1pf(expf(-x))) : log1pf(expf(x));
}

// ---------------------------------------------------------------------------
// Embedding conv (k=3, SAME) + BatchNorm + SiLU  ->  h (B*L, DMODEL) row-major
// ---------------------------------------------------------------------------
__global__ void k_embed(const float* __restrict__ x, const float* __restrict__ emb_w,
                        const float* __restrict__ gamma, const float* __restrict__ beta,
                        const float* __restrict__ mean, const float* __restrict__ var,
                        float* __restrict__ h) {
    const int m = blockIdx.x;             // b*L + l
    const int d = threadIdx.x;            // 0..255
    const int b = m >> 10;
    const int l = m & 1023;
    const float xm1 = (l > 0)    ? x[b * SEQL + l - 1] : 0.0f;
    const float x0  =              x[b * SEQL + l];
    const float xp1 = (l < 1023) ? x[b * SEQL + l + 1] : 0.0f;
    float c = xm1 * emb_w[d * 3 + 0] + x0 * emb_w[d * 3 + 1] + xp1 * emb_w[d * 3 + 2];
    const float inv = 1.0f / sqrtf(var[d] + 1e-5f);
    c = (c - mean[d]) * (inv * gamma[d]) + beta[d];
    h[(size_t)m * DMODEL + d] = siluf(c);
}

// ---------------------------------------------------------------------------
// fp32 tiled SGEMM, C[M,N] = A * B^T with B row-major [N][K].
// AT=false: A row-major [M][K] (lda = K-stride of a row).
// AT=true : A K-major  [K][M] (lda = stride between k-rows).
// ---------------------------------------------------------------------------
template <int BM, int BN, int BK, int TM, int TN, bool AT>
__global__ __launch_bounds__((BM / TM) * (BN / TN))
void sgemm(const float* __restrict__ A, int lda,
           const float* __restrict__ Bw, int ldb,
           float* __restrict__ C, int ldc, int K) {
    constexpr int TX = BN / TN;
    constexpr int TY = BM / TM;
    constexpr int NT = TX * TY;
    static_assert(NT == 256, "expect 256 threads");
    static_assert(BK % 4 == 0 && BM % 4 == 0, "");

    const int tid = threadIdx.x;
    const int tx = tid % TX;
    const int ty = tid / TX;
    const int m0 = blockIdx.y * BM;
    const int n0 = blockIdx.x * BN;

    __shared__ float As[BK][BM + 4];
    __shared__ float Bs[BK][BN + 4];

    float acc[TM][TN] = {};

    constexpr int AV = BM * BK / 4;
    constexpr int BV = BN * BK / 4;

    for (int kt = 0; kt < K; kt += BK) {
        if (AT) {
            for (int v = tid; v < AV; v += NT) {
                const int i4 = v % (BM / 4);
                const int kk = v / (BM / 4);
                const float4 a4 = *reinterpret_cast<const float4*>(
                    &A[(size_t)(kt + kk) * lda + m0 + i4 * 4]);
                As[kk][i4 * 4 + 0] = a4.x;
                As[kk][i4 * 4 + 1] = a4.y;
                As[kk][i4 * 4 + 2] = a4.z;
                As[kk][i4 * 4 + 3] = a4.w;
            }
        } else {
            for (int v = tid; v < AV; v += NT) {
                const int i = v / (BK / 4);
                const int jv = v % (BK / 4);
                const float4 a4 = *reinterpret_cast<const float4*>(
                    &A[(size_t)(m0 + i) * lda + kt + jv * 4]);
                As[jv * 4 + 0][i] = a4.x;
                As[jv * 4 + 1][i] = a4.y;
                As[jv * 4 + 2][i] = a4.z;
                As[jv * 4 + 3][i] = a4.w;
            }
        }
        for (int v = tid; v < BV; v += NT) {
            const int i = v / (BK / 4);
            const int jv = v % (BK / 4);
            const float4 b4 = *reinterpret_cast<const float4*>(
                &Bw[(size_t)(n0 + i) * ldb + kt + jv * 4]);
            Bs[jv * 4 + 0][i] = b4.x;
            Bs[jv * 4 + 1][i] = b4.y;
            Bs[jv * 4 + 2][i] = b4.z;
            Bs[jv * 4 + 3][i] = b4.w;
        }
        __syncthreads();
#pragma unroll
        for (int k = 0; k < BK; ++k) {
            float a[TM], b[TN];
#pragma unroll
            for (int i = 0; i < TM; ++i) a[i] = As[k][ty * TM + i];
#pragma unroll
            for (int j = 0; j < TN; ++j) b[j] = Bs[k][tx * TN + j];
#pragma unroll
            for (int i = 0; i < TM; ++i)
#pragma unroll
                for (int j = 0; j < TN; ++j) acc[i][j] = fmaf(a[i], b[j], acc[i][j]);
        }
        __syncthreads();
    }

#pragma unroll
    for (int i = 0; i < TM; ++i) {
        const int m = m0 + ty * TM + i;
#pragma unroll
        for (int j = 0; j < TN; ++j) {
            const int n = n0 + tx * TN + j;
            C[(size_t)m * ldc + n] = acc[i][j];
        }
    }
}

// ---------------------------------------------------------------------------
// Causal depthwise conv (k=4) + bias + SiLU, transposed layout.
// xzT[1024][4096]: rows 0..511 = xi. Writes xcT[512][4096]. Block=(d,b).
// ---------------------------------------------------------------------------
__global__ __launch_bounds__(256) void k_convT(const float* __restrict__ xzT,
                                               const float* __restrict__ cw,
                                               const float* __restrict__ cb,
                                               float* __restrict__ xcT) {
    const int d = blockIdx.x;
    const int b = blockIdx.y;
    const float w0 = cw[d * 4 + 0], w1 = cw[d * 4 + 1];
    const float w2 = cw[d * 4 + 2], w3 = cw[d * 4 + 3];
    const float bias = cb[d];
    const float* row = xzT + (size_t)d * MTOT + b * SEQL;
    float* orow = xcT + (size_t)d * MTOT + b * SEQL;
    for (int t = threadIdx.x; t < SEQL; t += 256) {
        float acc = fmaf(row[t], w3, bias);
        if (t >= 1) acc = fmaf(row[t - 1], w2, acc);
        if (t >= 2) acc = fmaf(row[t - 2], w1, acc);
        if (t >= 3) acc = fmaf(row[t - 3], w0, acc);
        orow[t] = siluf(acc);
    }
}

// ---------------------------------------------------------------------------
// Chunked parallel selective scan, transposed activations, fused dt_proj.
// One block per (d, b): 256 threads = (chunk c: 16) x (state n: 16).
// ---------------------------------------------------------------------------
__global__ __launch_bounds__(256) void k_scan3(
    const float* __restrict__ xcT, const float* __restrict__ xdbl,
    const float* __restrict__ xzT, const float* __restrict__ dtw,
    const float* __restrict__ dtb, const float* __restrict__ A_log,
    const float* __restrict__ D_skip, float* __restrict__ yT) {
    const int d = blockIdx.x;   // 0..511
    const int b = blockIdx.y;   // 0..3
    const int tid = threadIdx.x;
    const int c = tid >> 4;     // chunk 0..15
    const int n = tid & 15;     // state 0..15

    __shared__ float dt_s[1088];
    __shared__ float u_s[1088];
    __shared__ float zy_s[1088];              // z before Pass B, y after
    __shared__ float PS[16][16][2];

    const int mbase = b * SEQL;

    // block-uniform dt_proj weights for channel d
    const float4 w0 = *reinterpret_cast<const float4*>(&dtw[d * 16 + 0]);
    const float4 w1 = *reinterpret_cast<const float4*>(&dtw[d * 16 + 4]);
    const float4 w2 = *reinterpret_cast<const float4*>(&dtw[d * 16 + 8]);
    const float4 w3 = *reinterpret_cast<const float4*>(&dtw[d * 16 + 12]);
    const float bias = dtb[d];

    // stage: dt (fused dt_proj + softplus), u, z — all coalesced
    for (int ph = 0; ph < 4; ++ph) {
        const int t = ph * 256 + tid;
        const float* xr = &xdbl[(size_t)(mbase + t) * 48];
        const float4 a0 = *reinterpret_cast<const float4*>(&xr[0]);
        const float4 a1 = *reinterpret_cast<const float4*>(&xr[4]);
        const float4 a2 = *reinterpret_cast<const float4*>(&xr[8]);
        const float4 a3 = *reinterpret_cast<const float4*>(&xr[12]);
        float s = bias;
        s = fmaf(a0.x, w0.x, s); s = fmaf(a0.y, w0.y, s);
        s = fmaf(a0.z, w0.z, s); s = fmaf(a0.w, w0.w, s);
        s = fmaf(a1.x, w1.x, s); s = fmaf(a1.y, w1.y, s);
        s = fmaf(a1.z, w1.z, s); s = fmaf(a1.w, w1.w, s);
        s = fmaf(a2.x, w2.x, s); s = fmaf(a2.y, w2.y, s);
        s = fmaf(a2.z, w2.z, s); s = fmaf(a2.w, w2.w, s);
        s = fmaf(a3.x, w3.x, s); s = fmaf(a3.y, w3.y, s);
        s = fmaf(a3.z, w3.z, s); s = fmaf(a3.w, w3.w, s);
        dt_s[IDX(t)] = softplusf(s);
        u_s[IDX(t)]  = xcT[(size_t)d * MTOT + mbase + t];
        zy_s[IDX(t)] = xzT[(size_t)(DINNER + d) * MTOT + mbase + t];
    }
    __syncthreads();

    const float a = -expf(A_log[d * DSTATE + n]);
    const int t0 = c * 64;

    // ---- Pass A: chunk affine summary (P = prod dA, S = end state from 0) ----
    float P = 1.0f, S = 0.0f;
    {
        const float* Bp = &xdbl[(size_t)(mbase + t0) * 48 + DTRANK + n];
        float Bv = Bp[0];
        for (int j = 0; j < 64; ++j) {
            const float Bnx = (j < 63) ? Bp[(j + 1) * 48] : 0.0f;
            const int loc = j * 17 + c;
            const float dtv = dt_s[loc];
            const float e = expf(dtv * a);
            P *= e;
            S = fmaf(e, S, dtv * Bv * u_s[loc]);
            Bv = Bnx;
        }
    }
    PS[c][n][0] = P;
    PS[c][n][1] = S;
    __syncthreads();

    // exclusive affine prefix over chunks
    float h = 0.0f;
    for (int j = 0; j < c; ++j) h = fmaf(PS[j][n][0], h, PS[j][n][1]);

    // ---- Pass B: replay with correct init; fused (y + u*D) * silu(z) ----
    const float Dsk = D_skip[d];
    {
        const float* Bp = &xdbl[(size_t)(mbase + t0) * 48 + DTRANK + n];
        const float* Cp = Bp + DSTATE;
        float Bv = Bp[0];
        float Cv = Cp[0];
        for (int j = 0; j < 64; ++j) {
            float Bnx = 0.0f, Cnx = 0.0f;
            if (j < 63) { Bnx = Bp[(j + 1) * 48]; Cnx = Cp[(j + 1) * 48]; }
            const int loc = j * 17 + c;
            const float dtv = dt_s[loc];
            const float uv = u_s[loc];
            const float e = expf(dtv * a);
            h = fmaf(e, h, dtv * Bv * uv);
            float p = h * Cv;
            p += __shfl_xor(p, 1);
            p += __shfl_xor(p, 2);
            p += __shfl_xor(p, 4);
            p += __shfl_xor(p, 8);
            if (n == 0) {
                const float zv = zy_s[loc];
                zy_s[loc] = (p + uv * Dsk) * siluf(zv);
            }
            Bv = Bnx;
            Cv = Cnx;
        }
    }
    __syncthreads();

    // coalesced writeout of y row
    for (int ph = 0; ph < 4; ++ph) {
        const int t = ph * 256 + tid;
        yT[(size_t)d * MTOT + mbase + t] = zy_s[IDX(t)];
    }
}

// ---------------------------------------------------------------------------
// Column sums of last layer's out_proj_w: wsum[d] = sum_o w[o,d]
// ---------------------------------------------------------------------------
__global__ void k_wsum(const float* __restrict__ w, float* __restrict__ wsum) {
    const int d = threadIdx.x;  // 0..511
    float s = 0.0f;
    for (int o = 0; o < DMODEL; ++o) s += w[(size_t)o * DINNER + d];
    wsum[d] = s;
}

// ---------------------------------------------------------------------------
// Final: out[m] = sum_d yT[d][m] * wsum[d].  Block: 32 m's, 8 d-groups.
// ---------------------------------------------------------------------------
__global__ __launch_bounds__(256) void k_finalT(const float* __restrict__ yT,
                                                const float* __restrict__ wsum,
                                                float* __restrict__ out) {
    const int tid = threadIdx.x;
    const int dg = tid >> 5;       // 0..7
    const int ml = tid & 31;
    const int m = blockIdx.x * 32 + ml;
    float acc = 0.0f;
    const int dbase = dg * 64;
#pragma unroll 8
    for (int dd = 0; dd < 64; ++dd)
        acc = fmaf(yT[(size_t)(dbase + dd) * MTOT + m], wsum[dbase + dd], acc);
    __shared__ float red[8][33];
    red[dg][ml] = acc;
    __syncthreads();
    if (dg == 0) {
        float s = 0.0f;
#pragma unroll
        for (int g = 0; g < 8; ++g) s += red[g][ml];
        out[m] = s;
    }
}

// ---------------------------------------------------------------------------
extern "C" void kernel_launch(void* const* d_in, const int* in_sizes, int n_in,
                              void* d_out, int out_size, void* d_ws, size_t ws_size,
                              hipStream_t stream) {
    const float* x        = (const float*)d_in[0];
    const float* emb_w    = (const float*)d_in[2];
    const float* bn_gamma = (const float*)d_in[3];
    const float* bn_beta  = (const float*)d_in[4];
    const float* bn_mean  = (const float*)d_in[5];
    const float* bn_var   = (const float*)d_in[6];
    const float* in_proj_w  = (const float*)d_in[7];
    const float* conv_w     = (const float*)d_in[8];
    const float* conv_b     = (const float*)d_in[9];
    const float* x_proj_w   = (const float*)d_in[10];
    const float* dt_proj_w  = (const float*)d_in[11];
    const float* dt_proj_b  = (const float*)d_in[12];
    const float* A_log      = (const float*)d_in[13];
    const float* D_skip     = (const float*)d_in[14];
    const float* out_proj_w = (const float*)d_in[15];
    float* out = (float*)d_out;
    float* ws = (float*)d_ws;

    // workspace layout (floats)
    float* h    = ws;                              // 4096*256
    float* xzT  = h + (size_t)MTOT * DMODEL;       // 1024*4096
    float* xcT  = xzT + (size_t)1024 * MTOT;       // 512*4096
    float* xdbl = xcT + (size_t)DINNER * MTOT;     // 4096*48
    float* yT   = xdbl + (size_t)MTOT * 48;        // 512*4096
    float* wsum = yT + (size_t)DINNER * MTOT;      // 512

    k_embed<<<MTOT, DMODEL, 0, stream>>>(x, emb_w, bn_gamma, bn_beta, bn_mean, bn_var, h);

    for (int i = 0; i < NLAYERS; ++i) {
        const float* in_w  = in_proj_w + (size_t)i * 2 * DINNER * DMODEL;
        const float* cw    = conv_w + (size_t)i * DINNER * 4;
        const float* cb    = conv_b + (size_t)i * DINNER;
        const float* xp_w  = x_proj_w + (size_t)i * 48 * DINNER;
        const float* dtp_w = dt_proj_w + (size_t)i * DINNER * DTRANK;
        const float* dtp_b = dt_proj_b + (size_t)i * DINNER;
        const float* Al    = A_log + (size_t)i * DINNER * DSTATE;
        const float* Dsk   = D_skip + (size_t)i * DINNER;
        const float* o_w   = out_proj_w + (size_t)i * DMODEL * DINNER;

        // xzT[1024][4096] = in_w[1024,256] @ h[4096,256]^T   (C^T trick: swap A/B)
        sgemm<128, 64, 16, 8, 4, false><<<dim3(MTOT / 64, 1024 / 128), 256, 0, stream>>>(
            in_w, DMODEL, h, DMODEL, xzT, MTOT, DMODEL);

        // depthwise causal conv + silu (row-wise) -> xcT[512][4096]
        k_convT<<<dim3(DINNER, BATCH), 256, 0, stream>>>(xzT, cw, cb, xcT);

        // xdbl[4096,48] = xc @ xp_w^T, A = xcT (K-major)
        sgemm<128, 48, 16, 8, 3, true><<<dim3(1, MTOT / 128), 256, 0, stream>>>(
            xcT, MTOT, xp_w, DINNER, xdbl, 48, DINNER);

        // chunked parallel scan with fused dt_proj/softplus and epilogue -> yT
        k_scan3<<<dim3(DINNER, BATCH), 256, 0, stream>>>(
            xcT, xdbl, xzT, dtp_w, dtp_b, Al, Dsk, yT);

        if (i < NLAYERS - 1) {
            // h[4096,256] = y @ o_w^T, A = yT (K-major)
            sgemm<128, 64, 16, 8, 4, true><<<dim3(DMODEL / 64, MTOT / 128), 256, 0, stream>>>(
                yT, MTOT, o_w, DINNER, h, DMODEL, DINNER);
        } else {
            k_wsum<<<1, DINNER, 0, stream>>>(o_w, wsum);
            k_finalT<<<MTOT / 32, 256, 0, stream>>>(yT, wsum, out);
        }
    }
}

// Round 4
// 690.475 us; speedup vs baseline: 1.2860x; 1.2860x over previous
//
#include <hip/hip_runtime.h>
#include <math.h>

#define BATCH 4
#define SEQL 1024
#define DMODEL 256
#define DINNER 512
#define DSTATE 16
#define DTRANK 16
#define NLAYERS 4
#define MTOT (BATCH * SEQL)  // 4096

// LDS swizzle for time-series arrays: slot(t) = (t&63)*17 + (t>>6); max 1086
#define IDX(t) ((((t) & 63) * 17) + ((t) >> 6))

static __device__ __forceinline__ float siluf(float x) {
    return x / (1.0f + __expf(-x));
}
static __device__ __forceinline__ float softplusf(float x) {
    return (x > 0.0f) ? (x + __logf(1.0f + __expf(-x))) : __logf(1.0f + __expf(x));
}

// ---------------------------------------------------------------------------
// Embedding conv (k=3, SAME) + BatchNorm + SiLU  ->  h (B*L, DMODEL) row-major
// ---------------------------------------------------------------------------
__global__ void k_embed(const float* __restrict__ x, const float* __restrict__ emb_w,
                        const float* __restrict__ gamma, const float* __restrict__ beta,
                        const float* __restrict__ mean, const float* __restrict__ var,
                        float* __restrict__ h) {
    const int m = blockIdx.x;             // b*L + l
    const int d = threadIdx.x;            // 0..255
    const int b = m >> 10;
    const int l = m & 1023;
    const float xm1 = (l > 0)    ? x[b * SEQL + l - 1] : 0.0f;
    const float x0  =              x[b * SEQL + l];
    const float xp1 = (l < 1023) ? x[b * SEQL + l + 1] : 0.0f;
    float c = xm1 * emb_w[d * 3 + 0] + x0 * emb_w[d * 3 + 1] + xp1 * emb_w[d * 3 + 2];
    const float inv = 1.0f / sqrtf(var[d] + 1e-5f);
    c = (c - mean[d]) * (inv * gamma[d]) + beta[d];
    h[(size_t)m * DMODEL + d] = siluf(c);
}

// ---------------------------------------------------------------------------
// fp32 tiled SGEMM with register double-buffered staging.
// C[M,N] = A * B^T; B row-major [N][K] (ldb).
// AKM=false: A row-major [M][K]; AKM=true: A K-major [K][M] (lda = k-row stride).
// KSPLIT>1: blockIdx.z selects K-slice; writes to C + z*mstride.
// ---------------------------------------------------------------------------
template <int BM, int BN, int BK, int TM, int TN, bool AKM, int KTOT, int KSPLIT>
__global__ __launch_bounds__((BM / TM) * (BN / TN))
void sgemm2(const float* __restrict__ A, int lda,
            const float* __restrict__ Bw, int ldb,
            float* __restrict__ C, int ldc, int mstride) {
    constexpr int TX = BN / TN;
    constexpr int TY = BM / TM;
    constexpr int NT = TX * TY;
    static_assert(NT == 256, "expect 256 threads");
    constexpr int KS = KTOT / KSPLIT;
    static_assert(KS % BK == 0, "");
    constexpr int NSTEPS = KS / BK;
    constexpr int A4 = BM * BK / 4;
    constexpr int B4 = BN * BK / 4;
    constexpr int APT = (A4 + NT - 1) / NT;
    constexpr int BPT = (B4 + NT - 1) / NT;
    constexpr bool AG = (A4 % NT) != 0;
    constexpr bool BG = (B4 % NT) != 0;

    const int tid = threadIdx.x;
    const int tx = tid % TX;
    const int ty = tid / TX;
    const int m0 = blockIdx.y * BM;
    const int n0 = blockIdx.x * BN;
    const int kt0 = blockIdx.z * KS;

    __shared__ float As[BK][BM + 4];
    __shared__ float Bs[BK][BN + 4];

    float acc[TM][TN] = {};
    float4 ra[APT], rb[BPT];

    auto loadA = [&](int kt) {
#pragma unroll
        for (int u = 0; u < APT; ++u) {
            const int v = tid + u * NT;
            if (!AG || v < A4) {
                if (AKM) {
                    const int kk = v / (BM / 4);
                    const int i4 = v % (BM / 4);
                    ra[u] = *reinterpret_cast<const float4*>(
                        &A[(size_t)(kt + kk) * lda + m0 + i4 * 4]);
                } else {
                    const int i = v / (BK / 4);
                    const int jv = v % (BK / 4);
                    ra[u] = *reinterpret_cast<const float4*>(
                        &A[(size_t)(m0 + i) * lda + kt + jv * 4]);
                }
            }
        }
    };
    auto loadB = [&](int kt) {
#pragma unroll
        for (int u = 0; u < BPT; ++u) {
            const int v = tid + u * NT;
            if (!BG || v < B4) {
                const int i = v / (BK / 4);
                const int jv = v % (BK / 4);
                rb[u] = *reinterpret_cast<const float4*>(
                    &Bw[(size_t)(n0 + i) * ldb + kt + jv * 4]);
            }
        }
    };
    auto storeAB = [&]() {
#pragma unroll
        for (int u = 0; u < APT; ++u) {
            const int v = tid + u * NT;
            if (!AG || v < A4) {
                if (AKM) {
                    const int kk = v / (BM / 4);
                    const int i4 = v % (BM / 4);
                    *reinterpret_cast<float4*>(&As[kk][i4 * 4]) = ra[u];
                } else {
                    const int i = v / (BK / 4);
                    const int jv = v % (BK / 4);
                    As[jv * 4 + 0][i] = ra[u].x;
                    As[jv * 4 + 1][i] = ra[u].y;
                    As[jv * 4 + 2][i] = ra[u].z;
                    As[jv * 4 + 3][i] = ra[u].w;
                }
            }
        }
#pragma unroll
        for (int u = 0; u < BPT; ++u) {
            const int v = tid + u * NT;
            if (!BG || v < B4) {
                const int i = v / (BK / 4);
                const int jv = v % (BK / 4);
                Bs[jv * 4 + 0][i] = rb[u].x;
                Bs[jv * 4 + 1][i] = rb[u].y;
                Bs[jv * 4 + 2][i] = rb[u].z;
                Bs[jv * 4 + 3][i] = rb[u].w;
            }
        }
    };

    loadA(kt0);
    loadB(kt0);

    for (int s = 0; s < NSTEPS; ++s) {
        storeAB();
        __syncthreads();
        if (s + 1 < NSTEPS) {
            loadA(kt0 + (s + 1) * BK);
            loadB(kt0 + (s + 1) * BK);
        }
#pragma unroll
        for (int k = 0; k < BK; ++k) {
            float a[TM], b[TN];
#pragma unroll
            for (int i = 0; i < TM; ++i) a[i] = As[k][ty * TM + i];
#pragma unroll
            for (int j = 0; j < TN; ++j) b[j] = Bs[k][tx * TN + j];
#pragma unroll
            for (int i = 0; i < TM; ++i)
#pragma unroll
                for (int j = 0; j < TN; ++j) acc[i][j] = fmaf(a[i], b[j], acc[i][j]);
        }
        __syncthreads();
    }

    float* Cz = C + (size_t)blockIdx.z * mstride;
#pragma unroll
    for (int i = 0; i < TM; ++i) {
        const int m = m0 + ty * TM + i;
#pragma unroll
        for (int j = 0; j < TN; ++j) {
            const int n = n0 + tx * TN + j;
            Cz[(size_t)m * ldc + n] = acc[i][j];
        }
    }
}

// ---------------------------------------------------------------------------
// Reduce KSPLIT partial outputs (float4-wise): out = sum_z part[z]
// ---------------------------------------------------------------------------
__global__ __launch_bounds__(512) void k_kred(const float* __restrict__ part,
                                              float* __restrict__ out, int n4) {
    const int i = blockIdx.x * 512 + threadIdx.x;
    if (i >= n4) return;
    const float4* p = reinterpret_cast<const float4*>(part);
    float4 s = p[i];
    const float4 s1 = p[i + n4];
    const float4 s2 = p[i + 2 * n4];
    const float4 s3 = p[i + 3 * n4];
    s.x += s1.x + s2.x + s3.x;
    s.y += s1.y + s2.y + s3.y;
    s.z += s1.z + s2.z + s3.z;
    s.w += s1.w + s2.w + s3.w;
    reinterpret_cast<float4*>(out)[i] = s;
}

// ---------------------------------------------------------------------------
// Causal depthwise conv (k=4) + bias + SiLU, transposed layout.
// ---------------------------------------------------------------------------
__global__ __launch_bounds__(256) void k_convT(const float* __restrict__ xzT,
                                               const float* __restrict__ cw,
                                               const float* __restrict__ cb,
                                               float* __restrict__ xcT) {
    const int d = blockIdx.x;
    const int b = blockIdx.y;
    const float w0 = cw[d * 4 + 0], w1 = cw[d * 4 + 1];
    const float w2 = cw[d * 4 + 2], w3 = cw[d * 4 + 3];
    const float bias = cb[d];
    const float* row = xzT + (size_t)d * MTOT + b * SEQL;
    float* orow = xcT + (size_t)d * MTOT + b * SEQL;
    for (int t = threadIdx.x; t < SEQL; t += 256) {
        float acc = fmaf(row[t], w3, bias);
        if (t >= 1) acc = fmaf(row[t - 1], w2, acc);
        if (t >= 2) acc = fmaf(row[t - 2], w1, acc);
        if (t >= 3) acc = fmaf(row[t - 3], w0, acc);
        orow[t] = siluf(acc);
    }
}

// ---------------------------------------------------------------------------
// Chunked parallel selective scan, register-cached replay.
// Block (d, b): 512 threads = (chunk c: 32) x (state n: 16); 32 steps/chunk.
// Pass A: e[j], dBu[j] into registers; chunk summary (P, S).
// Prefix: exclusive affine combine over 32 chunks.
// Pass B: h = fma(e, h, dBu); p = h*C; 16-lane reduce; p -> LDS.
// Phase C: coalesced epilogue (p + u*D) * silu(z) -> yT.
// ---------------------------------------------------------------------------
#define CCH 32  // chunks
#define CT 32   // steps per chunk

__global__ __launch_bounds__(512) void k_scan4(
    const float* __restrict__ xcT, const float* __restrict__ xdbl,
    const float* __restrict__ xzT, const float* __restrict__ dtw,
    const float* __restrict__ dtb, const float* __restrict__ A_log,
    const float* __restrict__ D_skip, float* __restrict__ yT) {
    const int d = blockIdx.x;   // 0..511
    const int b = blockIdx.y;   // 0..3
    const int tid = threadIdx.x;
    const int c = tid >> 4;     // chunk 0..31
    const int n = tid & 15;     // state 0..15

    __shared__ float dt_s[1088];
    __shared__ float u_s[1088];
    __shared__ float p_s[1088];
    __shared__ float PS[CCH][17][2];

    const int mbase = b * SEQL;

    // block-uniform dt_proj weights for channel d
    const float4 w0 = *reinterpret_cast<const float4*>(&dtw[d * 16 + 0]);
    const float4 w1 = *reinterpret_cast<const float4*>(&dtw[d * 16 + 4]);
    const float4 w2 = *reinterpret_cast<const float4*>(&dtw[d * 16 + 8]);
    const float4 w3 = *reinterpret_cast<const float4*>(&dtw[d * 16 + 12]);
    const float bias = dtb[d];

    // stage dt (fused dt_proj + softplus) and u — coalesced
#pragma unroll
    for (int ph = 0; ph < 2; ++ph) {
        const int t = ph * 512 + tid;
        const float* xr = &xdbl[(size_t)(mbase + t) * 48];
        const float4 a0 = *reinterpret_cast<const float4*>(&xr[0]);
        const float4 a1 = *reinterpret_cast<const float4*>(&xr[4]);
        const float4 a2 = *reinterpret_cast<const float4*>(&xr[8]);
        const float4 a3 = *reinterpret_cast<const float4*>(&xr[12]);
        float s = bias;
        s = fmaf(a0.x, w0.x, s); s = fmaf(a0.y, w0.y, s);
        s = fmaf(a0.z, w0.z, s); s = fmaf(a0.w, w0.w, s);
        s = fmaf(a1.x, w1.x, s); s = fmaf(a1.y, w1.y, s);
        s = fmaf(a1.z, w1.z, s); s = fmaf(a1.w, w1.w, s);
        s = fmaf(a2.x, w2.x, s); s = fmaf(a2.y, w2.y, s);
        s = fmaf(a2.z, w2.z, s); s = fmaf(a2.w, w2.w, s);
        s = fmaf(a3.x, w3.x, s); s = fmaf(a3.y, w3.y, s);
        s = fmaf(a3.z, w3.z, s); s = fmaf(a3.w, w3.w, s);
        dt_s[IDX(t)] = softplusf(s);
        u_s[IDX(t)]  = xcT[(size_t)d * MTOT + mbase + t];
    }
    __syncthreads();

    const float a = -__expf(A_log[d * DSTATE + n]);
    const int t0 = c * CT;
    // LDS slot for step j of this chunk: j*17 + loc_base
    const int loc_base = (c & 1) * 544 + (c >> 1);

    const float* Bp = &xdbl[(size_t)(mbase + t0) * 48 + DTRANK + n];
    const float* Cp = Bp + DSTATE;

    float e[CT], dbu[CT];

    // ---- Pass A: cache e/dBu, chunk summary ----
    float P = 1.0f, S = 0.0f;
#pragma unroll
    for (int j = 0; j < CT; ++j) {
        const float Bv = Bp[j * 48];
        const int loc = j * 17 + loc_base;
        const float dtv = dt_s[loc];
        const float ee = __expf(dtv * a);
        e[j] = ee;
        dbu[j] = dtv * Bv * u_s[loc];
        P *= ee;
        S = fmaf(ee, S, dbu[j]);
    }
    PS[c][n][0] = P;
    PS[c][n][1] = S;
    __syncthreads();

    // exclusive affine prefix over chunks
    float h = 0.0f;
    for (int j = 0; j < c; ++j) h = fmaf(PS[j][n][0], h, PS[j][n][1]);

    // ---- Pass B: replay from registers ----
#pragma unroll
    for (int j = 0; j < CT; ++j) {
        h = fmaf(e[j], h, dbu[j]);
        float p = h * Cp[j * 48];
        p += __shfl_xor(p, 1);
        p += __shfl_xor(p, 2);
        p += __shfl_xor(p, 4);
        p += __shfl_xor(p, 8);
        if (n == 0) p_s[j * 17 + loc_base] = p;
    }
    __syncthreads();

    // ---- Phase C: coalesced epilogue ----
    const float Dsk = D_skip[d];
#pragma unroll
    for (int ph = 0; ph < 2; ++ph) {
        const int t = ph * 512 + tid;
        const float uv = u_s[IDX(t)];
        const float zv = xzT[(size_t)(DINNER + d) * MTOT + mbase + t];
        yT[(size_t)d * MTOT + mbase + t] = (p_s[IDX(t)] + uv * Dsk) * siluf(zv);
    }
}

// ---------------------------------------------------------------------------
// Column sums of last layer's out_proj_w: wsum[d] = sum_o w[o,d]
// ---------------------------------------------------------------------------
__global__ void k_wsum(const float* __restrict__ w, float* __restrict__ wsum) {
    const int d = threadIdx.x;  // 0..511
    float s = 0.0f;
    for (int o = 0; o < DMODEL; ++o) s += w[(size_t)o * DINNER + d];
    wsum[d] = s;
}

// ---------------------------------------------------------------------------
// Final: out[m] = sum_d yT[d][m] * wsum[d].  Block: 32 m's, 8 d-groups.
// ---------------------------------------------------------------------------
__global__ __launch_bounds__(256) void k_finalT(const float* __restrict__ yT,
                                                const float* __restrict__ wsum,
                                                float* __restrict__ out) {
    const int tid = threadIdx.x;
    const int dg = tid >> 5;       // 0..7
    const int ml = tid & 31;
    const int m = blockIdx.x * 32 + ml;
    float acc = 0.0f;
    const int dbase = dg * 64;
#pragma unroll 8
    for (int dd = 0; dd < 64; ++dd)
        acc = fmaf(yT[(size_t)(dbase + dd) * MTOT + m], wsum[dbase + dd], acc);
    __shared__ float red[8][33];
    red[dg][ml] = acc;
    __syncthreads();
    if (dg == 0) {
        float s = 0.0f;
#pragma unroll
        for (int g = 0; g < 8; ++g) s += red[g][ml];
        out[m] = s;
    }
}

// ---------------------------------------------------------------------------
extern "C" void kernel_launch(void* const* d_in, const int* in_sizes, int n_in,
                              void* d_out, int out_size, void* d_ws, size_t ws_size,
                              hipStream_t stream) {
    const float* x        = (const float*)d_in[0];
    const float* emb_w    = (const float*)d_in[2];
    const float* bn_gamma = (const float*)d_in[3];
    const float* bn_beta  = (const float*)d_in[4];
    const float* bn_mean  = (const float*)d_in[5];
    const float* bn_var   = (const float*)d_in[6];
    const float* in_proj_w  = (const float*)d_in[7];
    const float* conv_w     = (const float*)d_in[8];
    const float* conv_b     = (const float*)d_in[9];
    const float* x_proj_w   = (const float*)d_in[10];
    const float* dt_proj_w  = (const float*)d_in[11];
    const float* dt_proj_b  = (const float*)d_in[12];
    const float* A_log      = (const float*)d_in[13];
    const float* D_skip     = (const float*)d_in[14];
    const float* out_proj_w = (const float*)d_in[15];
    float* out = (float*)d_out;
    float* ws = (float*)d_ws;

    // workspace layout (floats)
    float* h    = ws;                              // 4096*256
    float* xzT  = h + (size_t)MTOT * DMODEL;       // 1024*4096
    float* xcT  = xzT + (size_t)1024 * MTOT;       // 512*4096
    float* xdbl = xcT + (size_t)DINNER * MTOT;     // 4096*48
    float* yT   = xdbl + (size_t)MTOT * 48;        // 512*4096
    float* part = yT + (size_t)DINNER * MTOT;      // 4*4096*48
    float* wsum = part + (size_t)4 * MTOT * 48;    // 512

    k_embed<<<MTOT, DMODEL, 0, stream>>>(x, emb_w, bn_gamma, bn_beta, bn_mean, bn_var, h);

    for (int i = 0; i < NLAYERS; ++i) {
        const float* in_w  = in_proj_w + (size_t)i * 2 * DINNER * DMODEL;
        const float* cw    = conv_w + (size_t)i * DINNER * 4;
        const float* cb    = conv_b + (size_t)i * DINNER;
        const float* xp_w  = x_proj_w + (size_t)i * 48 * DINNER;
        const float* dtp_w = dt_proj_w + (size_t)i * DINNER * DTRANK;
        const float* dtp_b = dt_proj_b + (size_t)i * DINNER;
        const float* Al    = A_log + (size_t)i * DINNER * DSTATE;
        const float* Dsk   = D_skip + (size_t)i * DINNER;
        const float* o_w   = out_proj_w + (size_t)i * DMODEL * DINNER;

        // xzT[1024][4096] = in_w[1024,256] @ h[4096,256]^T
        sgemm2<128, 128, 16, 8, 8, false, DMODEL, 1>
            <<<dim3(MTOT / 128, 1024 / 128, 1), 256, 0, stream>>>(
                in_w, DMODEL, h, DMODEL, xzT, MTOT, 0);

        // depthwise causal conv + silu -> xcT[512][4096]
        k_convT<<<dim3(DINNER, BATCH), 256, 0, stream>>>(xzT, cw, cb, xcT);

        // xdbl[4096,48] = xc @ xp_w^T, split-K=4 partials then reduce
        sgemm2<128, 48, 16, 8, 3, true, DINNER, 4>
            <<<dim3(1, MTOT / 128, 4), 256, 0, stream>>>(
                xcT, MTOT, xp_w, DINNER, part, 48, MTOT * 48);
        k_kred<<<(MTOT * 48 / 4 + 511) / 512, 512, 0, stream>>>(part, xdbl, MTOT * 48 / 4);

        // chunked parallel scan (fused dt_proj/softplus + epilogue) -> yT
        k_scan4<<<dim3(DINNER, BATCH), 512, 0, stream>>>(
            xcT, xdbl, xzT, dtp_w, dtp_b, Al, Dsk, yT);

        if (i < NLAYERS - 1) {
            // h[4096,256] = y @ o_w^T, A = yT (K-major)
            sgemm2<128, 64, 16, 8, 4, true, DINNER, 1>
                <<<dim3(DMODEL / 64, MTOT / 128, 1), 256, 0, stream>>>(
                    yT, MTOT, o_w, DINNER, h, DMODEL, 0);
        } else {
            k_wsum<<<1, DINNER, 0, stream>>>(o_w, wsum);
            k_finalT<<<MTOT / 32, 256, 0, stream>>>(yT, wsum, out);
        }
    }
}